// Round 4
// baseline (2347.156 us; speedup 1.0000x reference)
//
#include <hip/hip_runtime.h>
#include <math.h>

#define N_ENTS   50000
#define N_RELS   400        // 2*N_REL
#define D_IN0    100
#define DD       200
#define E_DIR    250000
#define E_TOT    500000
#define BATCH    512
#define NFILT    200
#define FLATK    39200
#define EPSV     1e-5f
#define NKEY     (2 * N_ENTS)   // (side, row) keys: in rows [0,50000), out rows [50000,100000)

// ---------------- workspace layout (float offsets) ----------------
#define WS_X1      ((size_t)0)
#define WS_X2      ((size_t)10000000)
#define WS_R1      ((size_t)20000000)
#define WS_R2      ((size_t)20080000)
#define WS_DINV_IN ((size_t)20160000)
#define WS_DINV_OUT ((size_t)20210000)
#define WS_STATS   ((size_t)20260000)   // 4096 floats
// stats sublayout
#define ST_L1_SUM   0
#define ST_L1_SQ    200
#define ST_L2_SUM   400
#define ST_L2_SQ    600
#define ST_BN0      800   // [0]=sum [1]=sq
#define ST_BN1_SUM  802
#define ST_BN1_SQ   1002
#define ST_BN2_SUM  1202
#define ST_BN2_SQ   1402
#define ST_S1       1602
#define ST_T1       1802
#define WS_IMGRAW  ((size_t)20264096)   // 512*400
#define WS_IMG     ((size_t)20468896)   // 512*400
#define WS_FCACC   ((size_t)20673696)   // 512*200
#define WS_HFIN    ((size_t)20776096)   // 512*200
#define WS_BIG     ((size_t)20878528)   // 30,000,000 floats (agg1/agg2/conv_raw)

// ---------------- degree / dinv ----------------
__global__ void deg_kernel(const int* __restrict__ ei, float* deg_in, float* deg_out) {
    int e = blockIdx.x * blockDim.x + threadIdx.x;
    if (e >= E_TOT) return;
    int row = ei[e];
    if (e < E_DIR) atomicAdd(&deg_in[row], 1.0f);
    else           atomicAdd(&deg_out[row], 1.0f);
}

__global__ void dinv_kernel(float* deg_in, float* deg_out) {
    int i = blockIdx.x * blockDim.x + threadIdx.x;
    if (i >= N_ENTS) return;
    float a = deg_in[i];
    deg_in[i]  = (a > 0.f) ? rsqrtf(a) : 0.f;
    float b = deg_out[i];
    deg_out[i] = (b > 0.f) ? rsqrtf(b) : 0.f;
}

// ---------------- CSR build: histogram -> scan -> fill ----------------
__global__ void hist_kernel(const int* __restrict__ ei, int* __restrict__ cnt) {
    int e = blockIdx.x * blockDim.x + threadIdx.x;
    if (e >= E_TOT) return;
    int key = ei[e] + ((e < E_DIR) ? 0 : N_ENTS);
    atomicAdd(&cnt[key], 1);
}

// single-block exclusive scan of cnt[NKEY] -> startp[NKEY+1]
__global__ __launch_bounds__(1024) void scan_kernel(const int* __restrict__ cnt,
                                                    int* __restrict__ startp) {
    __shared__ int part[1024];
    const int tid = threadIdx.x;
    const int per = (NKEY + 1023) / 1024;   // 98
    int b = tid * per;
    int e = b + per; if (e > NKEY) e = NKEY;
    if (b > NKEY) b = NKEY;
    int s = 0;
    for (int i = b; i < e; i++) s += cnt[i];
    part[tid] = s;
    __syncthreads();
    for (int off = 1; off < 1024; off <<= 1) {
        int v = (tid >= off) ? part[tid - off] : 0;
        __syncthreads();
        part[tid] += v;
        __syncthreads();
    }
    int run = (tid == 0) ? 0 : part[tid - 1];
    for (int i = b; i < e; i++) { startp[i] = run; run += cnt[i]; }
    if (e == NKEY) startp[NKEY] = run;
}

// fill sorted (col, type) arrays; advances startp[key] to segment END
__global__ void fill_kernel(const int* __restrict__ ei, const int* __restrict__ et,
                            int* __restrict__ startp,
                            int* __restrict__ col_s, int* __restrict__ t_s) {
    int e = blockIdx.x * blockDim.x + threadIdx.x;
    if (e >= E_TOT) return;
    int key = ei[e] + ((e < E_DIR) ? 0 : N_ENTS);
    int pos = atomicAdd(&startp[key], 1);
    col_s[pos] = ei[E_TOT + e];
    t_s[pos]   = et[e];
}

// ---------------- segmented reduction: agg[row, side] = sum over edges ----------------
template<int DIN, int STRIDE>
__global__ void seg_kernel(const int* __restrict__ startp, const int* __restrict__ cnt,
                           const int* __restrict__ col_s, const int* __restrict__ t_s,
                           const float* __restrict__ x, const float* __restrict__ r,
                           const float* __restrict__ dinv_in, const float* __restrict__ dinv_out,
                           float* __restrict__ agg) {
    int key = blockIdx.x;
    int d = threadIdx.x;
    if (d >= DIN) return;
    int end = startp[key];
    int beg = end - cnt[key];
    bool in_side = key < N_ENTS;
    int row = in_side ? key : key - N_ENTS;
    const float* dinv = in_side ? dinv_in : dinv_out;
    float acc = 0.f;
    for (int p = beg; p < end; p++) {
        int col = col_s[p];
        int t   = t_s[p];
        float sc = dinv[col];
        acc += x[(size_t)col * DIN + d] * r[(size_t)t * DIN + d] * sc;
    }
    agg[(size_t)row * STRIDE + (in_side ? 0 : DIN) + d] = acc;
}

// ---------------- loop compose: agg[n, 2*DIN + d] = x[n,d] * loop_rel[d] ----------------
template<int DIN, int STRIDE>
__global__ void loop_kernel(const float* __restrict__ x, const float* __restrict__ loop_rel,
                            float* agg) {
    int i = blockIdx.x * blockDim.x + threadIdx.x;
    if (i >= N_ENTS * DIN) return;
    int n = i / DIN, d = i % DIN;
    agg[(size_t)n * STRIDE + 2 * DIN + d] = x[i] * loop_rel[d];
}

// ---------------- layer GEMM v4: 128x128 tile, 8x8 micro, BK=16 double-buffered ----------------
// out[M=N_ENTS, N=200] = scaled(agg[M, 3*DIN]) @ [w_in; w_out; w_loop]
// v4: BK=16 halves barrier count vs v3; reg-staged prefetch; split-B conflict-free reads.
template<int DIN>
__launch_bounds__(256, 2)
__global__ void gemm_layer(const float* __restrict__ agg,
                           const float* __restrict__ w_in, const float* __restrict__ w_out,
                           const float* __restrict__ w_loop,
                           const float* __restrict__ dinv_in, const float* __restrict__ dinv_out,
                           float* __restrict__ out) {
    const int K = 3 * DIN;               // 300 or 600 (K % 4 == 0; NOT nec. % 16)
    __shared__ float As[2][16][132];     // [buf][k][m]
    __shared__ float Bs[2][16][132];     // [buf][k][n]
    const int m0 = blockIdx.x * 128;
    const int n0 = blockIdx.y * 128;
    const int tid = threadIdx.x;
    const int tx = tid & 15, ty = tid >> 4;
    // A staging: thread -> (row am, k offsets ak8, ak8+4)
    const int am  = tid >> 1;            // 0..127
    const int ak8 = (tid & 1) * 8;       // 0 or 8
    // B staging: thread -> (k row bk, col offsets bn8, bn8+4)
    const int bk  = tid >> 4;            // 0..15
    const int bn8 = (tid & 15) * 8;      // 0..120

    const int gm = m0 + am;
    const bool mval = gm < N_ENTS;
    const float scin  = mval ? dinv_in[gm]  : 0.f;
    const float scout = mval ? dinv_out[gm] : 0.f;
    const float* arow = &agg[(size_t)gm * K];
    const bool bv0 = (n0 + bn8 + 3) < DD;
    const bool bv1 = (n0 + bn8 + 7) < DD;

    // K%4==0 and kg%4==0: a float4 A-group is fully in or fully out of K.
    auto loadA4 = [&](int kg) -> float4 {
        float4 v = make_float4(0.f, 0.f, 0.f, 0.f);
        if (mval && kg < K) v = *(const float4*)&arow[kg];
        return v;
    };
    auto loadB4 = [&](int kg, int coff, bool nv) -> float4 {
        float4 v = make_float4(0.f, 0.f, 0.f, 0.f);
        if (kg < K && nv) {
            const float* wsrc; int kk;
            if (kg < DIN)          { wsrc = w_in;   kk = kg; }
            else if (kg < 2 * DIN) { wsrc = w_out;  kk = kg - DIN; }
            else                   { wsrc = w_loop; kk = kg - 2 * DIN; }
            v = *(const float4*)&wsrc[(size_t)kk * DD + n0 + bn8 + coff];
        }
        return v;
    };
    // region boundaries (DIN, 2*DIN) are %4==0, so one scale per float4
    auto stageAll = [&](int k0, float4 a0v, float4 a1v, float4 b0v, float4 b1v, int buf) {
        int kg0 = k0 + ak8, kg1 = kg0 + 4;
        float s0 = (kg0 < DIN) ? scin : ((kg0 < 2 * DIN) ? scout : 1.0f);
        float s1 = (kg1 < DIN) ? scin : ((kg1 < 2 * DIN) ? scout : 1.0f);
        As[buf][ak8 + 0][am] = a0v.x * s0;
        As[buf][ak8 + 1][am] = a0v.y * s0;
        As[buf][ak8 + 2][am] = a0v.z * s0;
        As[buf][ak8 + 3][am] = a0v.w * s0;
        As[buf][ak8 + 4][am] = a1v.x * s1;
        As[buf][ak8 + 5][am] = a1v.y * s1;
        As[buf][ak8 + 6][am] = a1v.z * s1;
        As[buf][ak8 + 7][am] = a1v.w * s1;
        *(float4*)&Bs[buf][bk][bn8]     = b0v;
        *(float4*)&Bs[buf][bk][bn8 + 4] = b1v;
    };

    float acc[8][8] = {};
    const int nsteps = (K + 15) / 16;    // 38 (K=600) or 19 (K=300)

    stageAll(0, loadA4(ak8), loadA4(ak8 + 4), loadB4(bk, 0, bv0), loadB4(bk, 4, bv1), 0);
    __syncthreads();
    int cur = 0;

    for (int s = 0; s < nsteps; s++) {
        const int nk0 = (s + 1) * 16;
        const bool have = (s + 1) < nsteps;
        float4 na0 = make_float4(0.f, 0.f, 0.f, 0.f), na1 = na0, nb0 = na0, nb1 = na0;
        if (have) {                      // issue next-tile loads; latency hides under FMAs
            na0 = loadA4(nk0 + ak8);
            na1 = loadA4(nk0 + ak8 + 4);
            nb0 = loadB4(nk0 + bk, 0, bv0);
            nb1 = loadB4(nk0 + bk, 4, bv1);
        }
#pragma unroll
        for (int k = 0; k < 16; k++) {
            float4 a0 = *(const float4*)&As[cur][k][ty * 8];
            float4 a1 = *(const float4*)&As[cur][k][ty * 8 + 4];
            float4 b0 = *(const float4*)&Bs[cur][k][tx * 4];        // 2-way banks (free)
            float4 b1 = *(const float4*)&Bs[cur][k][64 + tx * 4];
            float av[8] = {a0.x, a0.y, a0.z, a0.w, a1.x, a1.y, a1.z, a1.w};
            float bv[8] = {b0.x, b0.y, b0.z, b0.w, b1.x, b1.y, b1.z, b1.w};
#pragma unroll
            for (int i = 0; i < 8; i++)
#pragma unroll
                for (int j = 0; j < 8; j++) acc[i][j] += av[i] * bv[j];
        }
        if (have) {
            stageAll(nk0, na0, na1, nb0, nb1, cur ^ 1);
            __syncthreads();
            cur ^= 1;
        }
    }

    // epilogue: thread owns cols {nb0c..+3} and {nb1c..+3}
    const int nb0c = n0 + tx * 4;
    const int nb1c = n0 + 64 + tx * 4;
    const bool v0 = (nb0c + 3) < DD;
    const bool v1 = (nb1c + 3) < DD;
#pragma unroll
    for (int i = 0; i < 8; i++) {
        int m = m0 + ty * 8 + i;
        if (m < N_ENTS) {
            if (v0) *(float4*)&out[(size_t)m * DD + nb0c] = make_float4(acc[i][0], acc[i][1], acc[i][2], acc[i][3]);
            if (v1) *(float4*)&out[(size_t)m * DD + nb1c] = make_float4(acc[i][4], acc[i][5], acc[i][6], acc[i][7]);
        }
    }
}

// ---------------- per-feature stats: thread owns column f, private reg accumulation ----------------
__global__ void feat_stats_kernel(const float* __restrict__ x, int n_rows,
                                  float* __restrict__ sum, float* __restrict__ sq) {
    int f = threadIdx.x;            // 256 threads, active < 200
    if (f >= DD) return;
    int rows_per = (n_rows + gridDim.x - 1) / gridDim.x;
    int r0 = blockIdx.x * rows_per;
    int r1 = r0 + rows_per; if (r1 > n_rows) r1 = n_rows;
    float s = 0.f, q = 0.f;
    for (int rr = r0; rr < r1; rr++) {
        float v = x[(size_t)rr * DD + f];
        s += v; q += v * v;
    }
    atomicAdd(&sum[f], s);
    atomicAdd(&sq[f], q);
}

// ---------------- BN over nodes of y/3 + tanh, in place ----------------
__global__ void layer_apply_kernel(float* __restrict__ x,
                                   const float* __restrict__ sum, const float* __restrict__ sq,
                                   const float* __restrict__ g, const float* __restrict__ b) {
    int e = blockIdx.x * blockDim.x + threadIdx.x;
    if (e >= N_ENTS * DD) return;
    int f = e % DD;
    float mean = sum[f] * (1.0f / (3.0f * N_ENTS));
    float msq  = sq[f] * (1.0f / (9.0f * (float)N_ENTS));
    float var = msq - mean * mean;
    float v = (x[e] * (1.0f / 3.0f) - mean) * rsqrtf(var + EPSV) * g[f] + b[f];
    x[e] = tanhf(v);
}

// ---------------- relation transform: rout[400,200] = rprev[400,K] @ w_rel[K,200] ----------------
template<int KDIM>
__global__ void rel_kernel(const float* __restrict__ rprev, const float* __restrict__ w_rel,
                           float* __restrict__ rout) {
    int i = blockIdx.x;       // 0..399
    int j = threadIdx.x;      // 256, active < 200
    if (j >= DD) return;
    float acc = 0.f;
    for (int k = 0; k < KDIM; k++)
        acc += rprev[(size_t)i * KDIM + k] * w_rel[(size_t)k * DD + j];
    rout[(size_t)i * DD + j] = acc;
}

// ---------------- gather sub/rel embeddings into image + bn0 stats ----------------
__global__ void gather_kernel(const int* __restrict__ sub, const int* __restrict__ rel,
                              const float* __restrict__ x2, const float* __restrict__ r2,
                              float* __restrict__ imgraw, float* __restrict__ bn0acc) {
    int b = blockIdx.x;       // 512
    int t = threadIdx.x;      // 512
    float v = 0.f;
    if (t < 400) {
        int d = t >> 1;
        v = (t & 1) ? r2[(size_t)rel[b] * DD + d] : x2[(size_t)sub[b] * DD + d];
        imgraw[b * 400 + t] = v;
    }
    float sqv = v * v;
    for (int o = 32; o > 0; o >>= 1) {
        v   += __shfl_down(v, o, 64);
        sqv += __shfl_down(sqv, o, 64);
    }
    __shared__ float s1[8], s2l[8];
    int wid = t >> 6, lane = t & 63;
    if (lane == 0) { s1[wid] = v; s2l[wid] = sqv; }
    __syncthreads();
    if (t == 0) {
        float a = 0.f, c = 0.f;
        for (int w = 0; w < 8; w++) { a += s1[w]; c += s2l[w]; }
        atomicAdd(&bn0acc[0], a);
        atomicAdd(&bn0acc[1], c);
    }
}

__global__ void bn0_apply_kernel(const float* __restrict__ imgraw, const float* __restrict__ bn0acc,
                                 const float* __restrict__ g0, const float* __restrict__ b0,
                                 float* __restrict__ img) {
    int e = blockIdx.x * blockDim.x + threadIdx.x;
    if (e >= BATCH * 400) return;
    const float inv_n = 1.0f / (BATCH * 400);
    float m = bn0acc[0] * inv_n;
    float var = bn0acc[1] * inv_n - m * m;
    img[e] = (imgraw[e] - m) * rsqrtf(var + EPSV) * g0[0] + b0[0];
}

// ---------------- conv 7x7 VALID: [512,1,20,20] -> [512,200,14,14] ----------------
__global__ void conv_kernel(const float* __restrict__ img, const float* __restrict__ conv_w,
                            float* __restrict__ conv_raw) {
    __shared__ float simg[400];
    __shared__ float sw[9800];
    int b = blockIdx.x;
    int t = threadIdx.x;  // 256
    for (int i = t; i < 400; i += 256) simg[i] = img[b * 400 + i];
    for (int i = t; i < 9800; i += 256) sw[i] = conv_w[i];
    __syncthreads();
    for (int o = t; o < FLATK; o += 256) {
        int f = o / 196;
        int ij = o % 196;
        int i = ij / 14, j = ij % 14;
        const float* wp = &sw[f * 49];
        const float* ip = &simg[i * 20 + j];
        float acc = 0.f;
#pragma unroll
        for (int p = 0; p < 7; p++)
#pragma unroll
            for (int q = 0; q < 7; q++)
                acc += ip[p * 20 + q] * wp[p * 7 + q];
        conv_raw[(size_t)b * FLATK + o] = acc;
    }
}

// ---------------- bn1 stats: per-filter sum/sq over (b, i, j) ----------------
__global__ void bn1_stats_kernel(const float* __restrict__ conv_raw,
                                 float* __restrict__ sum, float* __restrict__ sq) {
    int blk = blockIdx.x;          // b*200 + f, 102400 blocks
    int f = blk % 200;
    size_t base = (size_t)blk * 196;
    int lane = threadIdx.x;        // 64
    float s = 0.f, q = 0.f;
    for (int i = lane; i < 196; i += 64) {
        float v = conv_raw[base + i];
        s += v; q += v * v;
    }
    for (int o = 32; o > 0; o >>= 1) {
        s += __shfl_down(s, o, 64);
        q += __shfl_down(q, o, 64);
    }
    if (lane == 0) { atomicAdd(&sum[f], s); atomicAdd(&sq[f], q); }
}

__global__ void bn1_coef_kernel(const float* __restrict__ sum, const float* __restrict__ sq,
                                const float* __restrict__ g1, const float* __restrict__ b1,
                                float* __restrict__ s1, float* __restrict__ t1) {
    int f = threadIdx.x;
    if (f >= 200) return;
    const float inv_n = 1.0f / (BATCH * 196);
    float m = sum[f] * inv_n;
    float var = sq[f] * inv_n - m * m;
    float s = g1[f] * rsqrtf(var + EPSV);
    s1[f] = s;
    t1[f] = b1[f] - m * s;
}

// ---------------- FC GEMM v2: M=64 x N=200(full) x BK=32, split-K Z=49 ----------------
__global__ void gemm_fc(const float* __restrict__ conv_raw, const float* __restrict__ fc_w,
                        const float* __restrict__ s1g, const float* __restrict__ t1g,
                        float* __restrict__ fc_acc) {
    __shared__ float As[32][68];
    __shared__ float Bs[32][256];
    __shared__ float Ss1[200], St1[200];
    const int m0   = blockIdx.x * 64;
    const int kbeg = blockIdx.y * 800;
    const int tid  = threadIdx.x;
    const int tx = tid & 63, ty = tid >> 6;
    const int ar  = tid >> 2;
    const int akc = (tid & 3) * 8;

    for (int i = tid; i < 200; i += 256) { Ss1[i] = s1g[i]; St1[i] = t1g[i]; }
    __syncthreads();

    float acc[16][4] = {};
    for (int k0 = 0; k0 < 800; k0 += 32) {
        {
            const float4* gp = (const float4*)&conv_raw[(size_t)(m0 + ar) * FLATK + kbeg + k0 + akc];
            float4 v0 = gp[0], v1 = gp[1];
            float tmp[8] = {v0.x, v0.y, v0.z, v0.w, v1.x, v1.y, v1.z, v1.w};
#pragma unroll
            for (int j = 0; j < 8; j++) {
                int kg = kbeg + k0 + akc + j;
                int f = kg / 196;
                As[akc + j][ar] = fmaxf(tmp[j] * Ss1[f] + St1[f], 0.f);
            }
        }
        {
            const float4* gp = (const float4*)&fc_w[(size_t)(kbeg + k0) * 200];
            for (int idx = tid; idx < 1600; idx += 256) {
                float4 v = gp[idx];
                int k = idx / 50, n4 = (idx % 50) * 4;
                *(float4*)&Bs[k][n4] = v;
            }
        }
        __syncthreads();
#pragma unroll 4
        for (int k = 0; k < 32; k++) {
            float4 a0 = *(const float4*)&As[k][ty * 16];
            float4 a1 = *(const float4*)&As[k][ty * 16 + 4];
            float4 a2 = *(const float4*)&As[k][ty * 16 + 8];
            float4 a3 = *(const float4*)&As[k][ty * 16 + 12];
            float av[16] = {a0.x, a0.y, a0.z, a0.w, a1.x, a1.y, a1.z, a1.w,
                            a2.x, a2.y, a2.z, a2.w, a3.x, a3.y, a3.z, a3.w};
            float bv[4] = {Bs[k][tx], Bs[k][tx + 64], Bs[k][tx + 128], Bs[k][tx + 192]};
#pragma unroll
            for (int i = 0; i < 16; i++)
#pragma unroll
                for (int j = 0; j < 4; j++) acc[i][j] += av[i] * bv[j];
        }
        __syncthreads();
    }
#pragma unroll
    for (int i = 0; i < 16; i++) {
        int m = m0 + ty * 16 + i;
#pragma unroll
        for (int j = 0; j < 4; j++) {
            int n = tx + 64 * j;
            if (n < DD) atomicAdd(&fc_acc[(size_t)m * DD + n], acc[i][j]);
        }
    }
}

// ---------------- bn2 stats over batch per feature ----------------
__global__ void bn2_stats_kernel(const float* __restrict__ fc_acc, const float* __restrict__ fc_b,
                                 float* __restrict__ sum, float* __restrict__ sq) {
    int f = blockIdx.x;      // 200
    int lane = threadIdx.x;  // 64
    float s = 0.f, q = 0.f;
    float bb = fc_b[f];
    for (int b = lane; b < BATCH; b += 64) {
        float v = fc_acc[(size_t)b * DD + f] + bb;
        s += v; q += v * v;
    }
    for (int o = 32; o > 0; o >>= 1) {
        s += __shfl_down(s, o, 64);
        q += __shfl_down(q, o, 64);
    }
    if (lane == 0) { sum[f] = s; sq[f] = q; }
}

__global__ void hfin_kernel(const float* __restrict__ fc_acc, const float* __restrict__ fc_b,
                            const float* __restrict__ sum, const float* __restrict__ sq,
                            const float* __restrict__ g2, const float* __restrict__ b2,
                            float* __restrict__ hfin) {
    int e = blockIdx.x * blockDim.x + threadIdx.x;
    if (e >= BATCH * DD) return;
    int f = e % DD;
    float m = sum[f] * (1.0f / BATCH);
    float var = sq[f] * (1.0f / BATCH) - m * m;
    float v = (fc_acc[e] + fc_b[f] - m) * rsqrtf(var + EPSV) * g2[f] + b2[f];
    hfin[e] = fmaxf(v, 0.f);
}

// ---------------- logits GEMM v3: 128x128 tile, double-buffered, split-B banks ----------------
__launch_bounds__(256, 2)
__global__ void gemm_logits(const float* __restrict__ hfin, const float* __restrict__ x2,
                            const float* __restrict__ ent_bias, float* __restrict__ out) {
    __shared__ float As[2][8][132];
    __shared__ float Bs[2][8][132];
    const int m0 = blockIdx.x * 128;
    const int n0 = blockIdx.y * 128;
    const int tid = threadIdx.x;
    const int tx = tid & 15, ty = tid >> 4;
    const int lr  = tid >> 1;          // 0..127
    const int lkc = (tid & 1) * 4;     // 0,4
    const int gn = n0 + lr;
    const bool nval = gn < N_ENTS;

    auto loadA = [&](int k0) -> float4 {
        return *(const float4*)&hfin[(size_t)(m0 + lr) * DD + k0 + lkc];
    };
    auto loadB = [&](int k0) -> float4 {
        float4 v = make_float4(0.f, 0.f, 0.f, 0.f);
        if (nval) v = *(const float4*)&x2[(size_t)gn * DD + k0 + lkc];
        return v;
    };
    auto stage = [&](float4 va, float4 vb, int buf) {
        As[buf][lkc + 0][lr] = va.x; As[buf][lkc + 1][lr] = va.y;
        As[buf][lkc + 2][lr] = va.z; As[buf][lkc + 3][lr] = va.w;
        Bs[buf][lkc + 0][lr] = vb.x; Bs[buf][lkc + 1][lr] = vb.y;
        Bs[buf][lkc + 2][lr] = vb.z; Bs[buf][lkc + 3][lr] = vb.w;
    };

    float acc[8][8] = {};
    stage(loadA(0), loadB(0), 0);
    __syncthreads();
    int cur = 0;

    for (int k0 = 0; k0 < DD; k0 += 8) {
        const int nxt = k0 + 8;
        const bool have = nxt < DD;
        float4 na = make_float4(0.f, 0.f, 0.f, 0.f), nb = na;
        if (have) { na = loadA(nxt); nb = loadB(nxt); }
#pragma unroll
        for (int k = 0; k < 8; k++) {
            float4 a0 = *(const float4*)&As[cur][k][ty * 8];
            float4 a1 = *(const float4*)&As[cur][k][ty * 8 + 4];
            float4 b0 = *(const float4*)&Bs[cur][k][tx * 4];
            float4 b1 = *(const float4*)&Bs[cur][k][64 + tx * 4];
            float av[8] = {a0.x, a0.y, a0.z, a0.w, a1.x, a1.y, a1.z, a1.w};
            float bv[8] = {b0.x, b0.y, b0.z, b0.w, b1.x, b1.y, b1.z, b1.w};
#pragma unroll
            for (int i = 0; i < 8; i++)
#pragma unroll
                for (int j = 0; j < 8; j++) acc[i][j] += av[i] * bv[j];
        }
        if (have) {
            stage(na, nb, cur ^ 1);
            __syncthreads();
            cur ^= 1;
        }
    }

    // epilogue: + ent_bias, sigmoid; cols {nb0..nb0+3} and {nb1..nb1+3} (4-aligned, N_ENTS%4==0)
    const int nb0 = n0 + tx * 4;
    const int nb1 = n0 + 64 + tx * 4;
    const bool v0 = (nb0 + 3) < N_ENTS;
    const bool v1 = (nb1 + 3) < N_ENTS;
    float4 e0 = make_float4(0.f, 0.f, 0.f, 0.f), e1 = e0;
    if (v0) e0 = *(const float4*)&ent_bias[nb0];
    if (v1) e1 = *(const float4*)&ent_bias[nb1];
    float eb[8] = {e0.x, e0.y, e0.z, e0.w, e1.x, e1.y, e1.z, e1.w};
#pragma unroll
    for (int i = 0; i < 8; i++) {
        int m = m0 + ty * 8 + i;   // always < BATCH
        float o[8];
#pragma unroll
        for (int j = 0; j < 8; j++) {
            float v = acc[i][j] + eb[j];
            o[j] = 1.0f / (1.0f + __expf(-v));
        }
        if (v0) *(float4*)&out[(size_t)m * N_ENTS + nb0] = make_float4(o[0], o[1], o[2], o[3]);
        if (v1) *(float4*)&out[(size_t)m * N_ENTS + nb1] = make_float4(o[4], o[5], o[6], o[7]);
    }
}

// ================= host launch =================
extern "C" void kernel_launch(void* const* d_in, const int* in_sizes, int n_in,
                              void* d_out, int out_size, void* d_ws, size_t ws_size,
                              hipStream_t stream) {
    const int*   sub        = (const int*)d_in[0];
    const int*   rel        = (const int*)d_in[1];
    const int*   edge_index = (const int*)d_in[2];
    const int*   edge_type  = (const int*)d_in[3];
    const float* init_embed = (const float*)d_in[4];
    const float* init_rel   = (const float*)d_in[5];
    const float* w_in1      = (const float*)d_in[6];
    const float* w_out1     = (const float*)d_in[7];
    const float* w_loop1    = (const float*)d_in[8];
    const float* w_rel1     = (const float*)d_in[9];
    const float* loop_rel1  = (const float*)d_in[10];
    const float* bn_g1      = (const float*)d_in[11];
    const float* bn_b1      = (const float*)d_in[12];
    const float* w_in2      = (const float*)d_in[13];
    const float* w_out2     = (const float*)d_in[14];
    const float* w_loop2    = (const float*)d_in[15];
    const float* w_rel2     = (const float*)d_in[16];
    const float* loop_rel2  = (const float*)d_in[17];
    const float* bn_g2      = (const float*)d_in[18];
    const float* bn_b2      = (const float*)d_in[19];
    const float* conv_w     = (const float*)d_in[20];
    const float* bn0_g      = (const float*)d_in[21];
    const float* bn0_b      = (const float*)d_in[22];
    const float* bn1_g      = (const float*)d_in[23];
    const float* bn1_b      = (const float*)d_in[24];
    const float* bn2_g      = (const float*)d_in[25];
    const float* bn2_b      = (const float*)d_in[26];
    const float* fc_w       = (const float*)d_in[27];
    const float* fc_b       = (const float*)d_in[28];
    const float* ent_bias   = (const float*)d_in[29];

    float* ws = (float*)d_ws;
    float* x1       = ws + WS_X1;
    float* x2       = ws + WS_X2;
    float* r1       = ws + WS_R1;
    float* r2       = ws + WS_R2;
    float* dinv_in  = ws + WS_DINV_IN;
    float* dinv_out = ws + WS_DINV_OUT;
    float* stats    = ws + WS_STATS;
    float* imgraw   = ws + WS_IMGRAW;
    float* img      = ws + WS_IMG;
    float* fc_acc   = ws + WS_FCACC;
    float* hfin     = ws + WS_HFIN;
    float* big      = ws + WS_BIG;   // agg1 (15M) / agg2 (30M) / conv_raw (20.07M)
    float* out      = (float*)d_out;

    // CSR sort scratch lives in the x2 region (free until gemm_layer<200> writes x2)
    int* cnt    = (int*)x2;                 // NKEY
    int* startp = cnt + NKEY;               // NKEY+1
    int* col_s  = startp + NKEY + 1;        // E_TOT
    int* t_s    = col_s + E_TOT;            // E_TOT

    // zero accumulators (ws is poisoned 0xAA before every call)
    hipMemsetAsync(dinv_in, 0, 2 * N_ENTS * sizeof(float), stream);
    hipMemsetAsync(stats, 0, 4096 * sizeof(float), stream);
    hipMemsetAsync(fc_acc, 0, BATCH * DD * sizeof(float), stream);
    hipMemsetAsync(cnt, 0, NKEY * sizeof(int), stream);

    // degrees -> dinv
    deg_kernel<<<(E_TOT + 255) / 256, 256, 0, stream>>>(edge_index, dinv_in, dinv_out);
    dinv_kernel<<<(N_ENTS + 255) / 256, 256, 0, stream>>>(dinv_in, dinv_out);

    // CSR build (once; reused by both layers)
    hist_kernel<<<(E_TOT + 255) / 256, 256, 0, stream>>>(edge_index, cnt);
    scan_kernel<<<1, 1024, 0, stream>>>(cnt, startp);
    fill_kernel<<<(E_TOT + 255) / 256, 256, 0, stream>>>(edge_index, edge_type, startp, col_s, t_s);

    // ---- layer 1 ----
    seg_kernel<100, 300><<<NKEY, 128, 0, stream>>>(startp, cnt, col_s, t_s, init_embed,
                                                   init_rel, dinv_in, dinv_out, big);
    loop_kernel<100, 300><<<(N_ENTS * 100 + 255) / 256, 256, 0, stream>>>(init_embed, loop_rel1, big);
    {
        dim3 g((N_ENTS + 127) / 128, (DD + 127) / 128);
        gemm_layer<100><<<g, 256, 0, stream>>>(big, w_in1, w_out1, w_loop1, dinv_in, dinv_out, x1);
    }
    feat_stats_kernel<<<256, 256, 0, stream>>>(x1, N_ENTS, stats + ST_L1_SUM, stats + ST_L1_SQ);
    layer_apply_kernel<<<(N_ENTS * DD + 255) / 256, 256, 0, stream>>>(x1, stats + ST_L1_SUM,
                                                                      stats + ST_L1_SQ, bn_g1, bn_b1);
    rel_kernel<100><<<N_RELS, 256, 0, stream>>>(init_rel, w_rel1, r1);

    // ---- layer 2 ----
    seg_kernel<200, 600><<<NKEY, 256, 0, stream>>>(startp, cnt, col_s, t_s, x1, r1,
                                                   dinv_in, dinv_out, big);
    loop_kernel<200, 600><<<(N_ENTS * 200 + 255) / 256, 256, 0, stream>>>(x1, loop_rel2, big);
    {
        dim3 g((N_ENTS + 127) / 128, (DD + 127) / 128);
        gemm_layer<200><<<g, 256, 0, stream>>>(big, w_in2, w_out2, w_loop2, dinv_in, dinv_out, x2);
    }
    feat_stats_kernel<<<256, 256, 0, stream>>>(x2, N_ENTS, stats + ST_L2_SUM, stats + ST_L2_SQ);
    layer_apply_kernel<<<(N_ENTS * DD + 255) / 256, 256, 0, stream>>>(x2, stats + ST_L2_SUM,
                                                                      stats + ST_L2_SQ, bn_g2, bn_b2);
    rel_kernel<200><<<N_RELS, 256, 0, stream>>>(r1, w_rel2, r2);

    // ---- ConvE scorer ----
    gather_kernel<<<BATCH, 512, 0, stream>>>(sub, rel, x2, r2, imgraw, stats + ST_BN0);
    bn0_apply_kernel<<<(BATCH * 400 + 255) / 256, 256, 0, stream>>>(imgraw, stats + ST_BN0,
                                                                    bn0_g, bn0_b, img);
    conv_kernel<<<BATCH, 256, 0, stream>>>(img, conv_w, big);   // big = conv_raw now
    bn1_stats_kernel<<<BATCH * NFILT, 64, 0, stream>>>(big, stats + ST_BN1_SUM, stats + ST_BN1_SQ);
    bn1_coef_kernel<<<1, 256, 0, stream>>>(stats + ST_BN1_SUM, stats + ST_BN1_SQ, bn1_g, bn1_b,
                                           stats + ST_S1, stats + ST_T1);
    {
        dim3 g(BATCH / 64, 49);   // split-K: 49 chunks of 800
        gemm_fc<<<g, 256, 0, stream>>>(big, fc_w, stats + ST_S1, stats + ST_T1, fc_acc);
    }
    bn2_stats_kernel<<<NFILT, 64, 0, stream>>>(fc_acc, fc_b, stats + ST_BN2_SUM, stats + ST_BN2_SQ);
    hfin_kernel<<<(BATCH * DD + 255) / 256, 256, 0, stream>>>(fc_acc, fc_b, stats + ST_BN2_SUM,
                                                              stats + ST_BN2_SQ, bn2_g, bn2_b, hfin);
    {
        dim3 g(BATCH / 128, (N_ENTS + 127) / 128);
        gemm_logits<<<g, 256, 0, stream>>>(hfin, x2, ent_bias, out);
    }
}

// Round 5
// 1954.756 us; speedup vs baseline: 1.2007x; 1.2007x over previous
//
#include <hip/hip_runtime.h>
#include <math.h>

#define N_ENTS   50000
#define N_RELS   400        // 2*N_REL
#define D_IN0    100
#define DD       200
#define E_DIR    250000
#define E_TOT    500000
#define BATCH    512
#define NFILT    200
#define FLATK    39200
#define EPSV     1e-5f
#define NKEY     (2 * N_ENTS)   // (side, row) keys: in rows [0,50000), out rows [50000,100000)

// ---------------- workspace layout (float offsets) ----------------
#define WS_X1      ((size_t)0)
#define WS_X2      ((size_t)10000000)
#define WS_R1      ((size_t)20000000)
#define WS_R2      ((size_t)20080000)
#define WS_DINV_IN ((size_t)20160000)
#define WS_DINV_OUT ((size_t)20210000)
#define WS_STATS   ((size_t)20260000)   // 4096 floats
// stats sublayout
#define ST_L1_SUM   0
#define ST_L1_SQ    200
#define ST_L2_SUM   400
#define ST_L2_SQ    600
#define ST_BN0      800   // [0]=sum [1]=sq
#define ST_BN1_SUM  802
#define ST_BN1_SQ   1002
#define ST_BN2_SUM  1202
#define ST_BN2_SQ   1402
#define ST_S1       1602
#define ST_T1       1802
#define WS_IMGRAW  ((size_t)20264096)   // 512*400
#define WS_IMG     ((size_t)20468896)   // 512*400
#define WS_FCACC   ((size_t)20673696)   // 512*200
#define WS_HFIN    ((size_t)20776096)   // 512*200
#define WS_BIG     ((size_t)20878528)   // 30,000,000 floats (agg1/agg2/conv_raw)

// ---------------- degree / dinv ----------------
__global__ void deg_kernel(const int* __restrict__ ei, float* deg_in, float* deg_out) {
    int e = blockIdx.x * blockDim.x + threadIdx.x;
    if (e >= E_TOT) return;
    int row = ei[e];
    if (e < E_DIR) atomicAdd(&deg_in[row], 1.0f);
    else           atomicAdd(&deg_out[row], 1.0f);
}

__global__ void dinv_kernel(float* deg_in, float* deg_out) {
    int i = blockIdx.x * blockDim.x + threadIdx.x;
    if (i >= N_ENTS) return;
    float a = deg_in[i];
    deg_in[i]  = (a > 0.f) ? rsqrtf(a) : 0.f;
    float b = deg_out[i];
    deg_out[i] = (b > 0.f) ? rsqrtf(b) : 0.f;
}

// ---------------- CSR build: histogram -> scan -> fill ----------------
__global__ void hist_kernel(const int* __restrict__ ei, int* __restrict__ cnt) {
    int e = blockIdx.x * blockDim.x + threadIdx.x;
    if (e >= E_TOT) return;
    int key = ei[e] + ((e < E_DIR) ? 0 : N_ENTS);
    atomicAdd(&cnt[key], 1);
}

// single-block exclusive scan of cnt[NKEY] -> startp[NKEY+1]
__global__ __launch_bounds__(1024) void scan_kernel(const int* __restrict__ cnt,
                                                    int* __restrict__ startp) {
    __shared__ int part[1024];
    const int tid = threadIdx.x;
    const int per = (NKEY + 1023) / 1024;   // 98
    int b = tid * per;
    int e = b + per; if (e > NKEY) e = NKEY;
    if (b > NKEY) b = NKEY;
    int s = 0;
    for (int i = b; i < e; i++) s += cnt[i];
    part[tid] = s;
    __syncthreads();
    for (int off = 1; off < 1024; off <<= 1) {
        int v = (tid >= off) ? part[tid - off] : 0;
        __syncthreads();
        part[tid] += v;
        __syncthreads();
    }
    int run = (tid == 0) ? 0 : part[tid - 1];
    for (int i = b; i < e; i++) { startp[i] = run; run += cnt[i]; }
    if (e == NKEY) startp[NKEY] = run;
}

// fill sorted (col, type) arrays; advances startp[key] to segment END
__global__ void fill_kernel(const int* __restrict__ ei, const int* __restrict__ et,
                            int* __restrict__ startp,
                            int* __restrict__ col_s, int* __restrict__ t_s) {
    int e = blockIdx.x * blockDim.x + threadIdx.x;
    if (e >= E_TOT) return;
    int key = ei[e] + ((e < E_DIR) ? 0 : N_ENTS);
    int pos = atomicAdd(&startp[key], 1);
    col_s[pos] = ei[E_TOT + e];
    t_s[pos]   = et[e];
}

// ---------------- segmented reduction: agg[row, side] = sum over edges ----------------
template<int DIN, int STRIDE>
__global__ void seg_kernel(const int* __restrict__ startp, const int* __restrict__ cnt,
                           const int* __restrict__ col_s, const int* __restrict__ t_s,
                           const float* __restrict__ x, const float* __restrict__ r,
                           const float* __restrict__ dinv_in, const float* __restrict__ dinv_out,
                           float* __restrict__ agg) {
    int key = blockIdx.x;
    int d = threadIdx.x;
    if (d >= DIN) return;
    int end = startp[key];
    int beg = end - cnt[key];
    bool in_side = key < N_ENTS;
    int row = in_side ? key : key - N_ENTS;
    const float* dinv = in_side ? dinv_in : dinv_out;
    float acc = 0.f;
    for (int p = beg; p < end; p++) {
        int col = col_s[p];
        int t   = t_s[p];
        float sc = dinv[col];
        acc += x[(size_t)col * DIN + d] * r[(size_t)t * DIN + d] * sc;
    }
    agg[(size_t)row * STRIDE + (in_side ? 0 : DIN) + d] = acc;
}

// ---------------- layer GEMM v5: v3 structure (BK=8 dbuf, split-B) + fused loop-compose ----------------
// out[M=N_ENTS, N=200] = [scaled(agg[M, 2*DIN]) | x*loop_rel] @ [w_in; w_out; w_loop]
// agg has stride 2*DIN (in/out halves only); the loop third is computed on the fly from x.
template<int DIN>
__launch_bounds__(256, 2)
__global__ void gemm_layer(const float* __restrict__ agg,
                           const float* __restrict__ x, const float* __restrict__ loop_rel,
                           const float* __restrict__ w_in, const float* __restrict__ w_out,
                           const float* __restrict__ w_loop,
                           const float* __restrict__ dinv_in, const float* __restrict__ dinv_out,
                           float* __restrict__ out) {
    const int K = 3 * DIN;
    __shared__ float As[2][8][132];   // [buf][k][m]
    __shared__ float Bs[2][8][132];   // [buf][k][n]
    const int m0 = blockIdx.x * 128;
    const int n0 = blockIdx.y * 128;
    const int tid = threadIdx.x;
    const int tx = tid & 15, ty = tid >> 4;
    const int am  = tid >> 1;          // A row 0..127
    const int akc = (tid & 1) * 4;     // A k-offset 0,4
    const int bk = tid >> 5;           // B k 0..7
    const int bn = (tid & 31) * 4;     // B n-offset 0..124

    const int gm = m0 + am;
    const bool mval = gm < N_ENTS;
    const float scin  = mval ? dinv_in[gm]  : 0.f;
    const float scout = mval ? dinv_out[gm] : 0.f;
    const float* arow = &agg[(size_t)gm * (2 * DIN)];
    const float* xrow = &x[(size_t)gm * DIN];
    const bool bnval = (n0 + bn + 3) < DD;

    // 4-groups never straddle region boundaries (DIN, 2*DIN are %4==0)
    auto loadA = [&](int k0) -> float4 {
        int kg = k0 + akc;
        float4 v = make_float4(0.f, 0.f, 0.f, 0.f);
        if (mval && kg < K) {
            if (kg < 2 * DIN) {
                v = *(const float4*)&arow[kg];
            } else {
                int kk = kg - 2 * DIN;
                float4 xv = *(const float4*)&xrow[kk];
                float4 lv = *(const float4*)&loop_rel[kk];
                v = make_float4(xv.x * lv.x, xv.y * lv.y, xv.z * lv.z, xv.w * lv.w);
            }
        }
        return v;
    };
    auto loadB = [&](int k0) -> float4 {
        int kg = k0 + bk;
        float4 v = make_float4(0.f, 0.f, 0.f, 0.f);
        if (kg < K && bnval) {
            const float* wsrc; int kk;
            if (kg < DIN)          { wsrc = w_in;   kk = kg; }
            else if (kg < 2 * DIN) { wsrc = w_out;  kk = kg - DIN; }
            else                   { wsrc = w_loop; kk = kg - 2 * DIN; }
            v = *(const float4*)&wsrc[(size_t)kk * DD + n0 + bn];
        }
        return v;
    };
    auto stageA = [&](int k0, float4 v, int buf) {
        int kg = k0 + akc;
        float s = (kg < DIN) ? scin : ((kg < 2 * DIN) ? scout : 1.0f);
        As[buf][akc + 0][am] = v.x * s;
        As[buf][akc + 1][am] = v.y * s;
        As[buf][akc + 2][am] = v.z * s;
        As[buf][akc + 3][am] = v.w * s;
    };
    auto stageB = [&](float4 v, int buf) {
        *(float4*)&Bs[buf][bk][bn] = v;
    };

    float acc[8][8] = {};

    stageA(0, loadA(0), 0);
    stageB(loadB(0), 0);
    __syncthreads();
    int cur = 0;

    for (int k0 = 0; k0 < K; k0 += 8) {
        const int nxt = k0 + 8;
        const bool have = nxt < K;
        float4 na = make_float4(0.f, 0.f, 0.f, 0.f), nb = na;
        if (have) { na = loadA(nxt); nb = loadB(nxt); }   // latency hides under FMAs
#pragma unroll
        for (int k = 0; k < 8; k++) {
            float4 a0 = *(const float4*)&As[cur][k][ty * 8];
            float4 a1 = *(const float4*)&As[cur][k][ty * 8 + 4];
            float4 b0 = *(const float4*)&Bs[cur][k][tx * 4];        // 2-way banks (free)
            float4 b1 = *(const float4*)&Bs[cur][k][64 + tx * 4];
            float av[8] = {a0.x, a0.y, a0.z, a0.w, a1.x, a1.y, a1.z, a1.w};
            float bv[8] = {b0.x, b0.y, b0.z, b0.w, b1.x, b1.y, b1.z, b1.w};
#pragma unroll
            for (int i = 0; i < 8; i++)
#pragma unroll
                for (int j = 0; j < 8; j++) acc[i][j] += av[i] * bv[j];
        }
        if (have) {
            stageA(nxt, na, cur ^ 1);
            stageB(nb, cur ^ 1);
            __syncthreads();
            cur ^= 1;
        }
    }

    // epilogue: thread owns cols {nb0..nb0+3} and {nb1..nb1+3}
    const int nb0 = n0 + tx * 4;
    const int nb1 = n0 + 64 + tx * 4;
    const bool v0 = (nb0 + 3) < DD;
    const bool v1 = (nb1 + 3) < DD;
#pragma unroll
    for (int i = 0; i < 8; i++) {
        int m = m0 + ty * 8 + i;
        if (m < N_ENTS) {
            if (v0) *(float4*)&out[(size_t)m * DD + nb0] = make_float4(acc[i][0], acc[i][1], acc[i][2], acc[i][3]);
            if (v1) *(float4*)&out[(size_t)m * DD + nb1] = make_float4(acc[i][4], acc[i][5], acc[i][6], acc[i][7]);
        }
    }
}

// ---------------- per-feature stats: thread owns column f, private reg accumulation ----------------
__global__ void feat_stats_kernel(const float* __restrict__ x, int n_rows,
                                  float* __restrict__ sum, float* __restrict__ sq) {
    int f = threadIdx.x;            // 256 threads, active < 200
    if (f >= DD) return;
    int rows_per = (n_rows + gridDim.x - 1) / gridDim.x;
    int r0 = blockIdx.x * rows_per;
    int r1 = r0 + rows_per; if (r1 > n_rows) r1 = n_rows;
    float s = 0.f, q = 0.f;
    for (int rr = r0; rr < r1; rr++) {
        float v = x[(size_t)rr * DD + f];
        s += v; q += v * v;
    }
    atomicAdd(&sum[f], s);
    atomicAdd(&sq[f], q);
}

// ---------------- BN over nodes of y/3 + tanh, in place ----------------
__global__ void layer_apply_kernel(float* __restrict__ x,
                                   const float* __restrict__ sum, const float* __restrict__ sq,
                                   const float* __restrict__ g, const float* __restrict__ b) {
    int e = blockIdx.x * blockDim.x + threadIdx.x;
    if (e >= N_ENTS * DD) return;
    int f = e % DD;
    float mean = sum[f] * (1.0f / (3.0f * N_ENTS));
    float msq  = sq[f] * (1.0f / (9.0f * (float)N_ENTS));
    float var = msq - mean * mean;
    float v = (x[e] * (1.0f / 3.0f) - mean) * rsqrtf(var + EPSV) * g[f] + b[f];
    x[e] = tanhf(v);
}

// ---------------- relation transform: rout[400,200] = rprev[400,K] @ w_rel[K,200] ----------------
template<int KDIM>
__global__ void rel_kernel(const float* __restrict__ rprev, const float* __restrict__ w_rel,
                           float* __restrict__ rout) {
    int i = blockIdx.x;       // 0..399
    int j = threadIdx.x;      // 256, active < 200
    if (j >= DD) return;
    float acc = 0.f;
    for (int k = 0; k < KDIM; k++)
        acc += rprev[(size_t)i * KDIM + k] * w_rel[(size_t)k * DD + j];
    rout[(size_t)i * DD + j] = acc;
}

// ---------------- gather sub/rel embeddings into image + bn0 stats ----------------
__global__ void gather_kernel(const int* __restrict__ sub, const int* __restrict__ rel,
                              const float* __restrict__ x2, const float* __restrict__ r2,
                              float* __restrict__ imgraw, float* __restrict__ bn0acc) {
    int b = blockIdx.x;       // 512
    int t = threadIdx.x;      // 512
    float v = 0.f;
    if (t < 400) {
        int d = t >> 1;
        v = (t & 1) ? r2[(size_t)rel[b] * DD + d] : x2[(size_t)sub[b] * DD + d];
        imgraw[b * 400 + t] = v;
    }
    float sqv = v * v;
    for (int o = 32; o > 0; o >>= 1) {
        v   += __shfl_down(v, o, 64);
        sqv += __shfl_down(sqv, o, 64);
    }
    __shared__ float s1[8], s2l[8];
    int wid = t >> 6, lane = t & 63;
    if (lane == 0) { s1[wid] = v; s2l[wid] = sqv; }
    __syncthreads();
    if (t == 0) {
        float a = 0.f, c = 0.f;
        for (int w = 0; w < 8; w++) { a += s1[w]; c += s2l[w]; }
        atomicAdd(&bn0acc[0], a);
        atomicAdd(&bn0acc[1], c);
    }
}

__global__ void bn0_apply_kernel(const float* __restrict__ imgraw, const float* __restrict__ bn0acc,
                                 const float* __restrict__ g0, const float* __restrict__ b0,
                                 float* __restrict__ img) {
    int e = blockIdx.x * blockDim.x + threadIdx.x;
    if (e >= BATCH * 400) return;
    const float inv_n = 1.0f / (BATCH * 400);
    float m = bn0acc[0] * inv_n;
    float var = bn0acc[1] * inv_n - m * m;
    img[e] = (imgraw[e] - m) * rsqrtf(var + EPSV) * g0[0] + b0[0];
}

// ---------------- conv 7x7 VALID: [512,1,20,20] -> [512,200,14,14] ----------------
__global__ void conv_kernel(const float* __restrict__ img, const float* __restrict__ conv_w,
                            float* __restrict__ conv_raw) {
    __shared__ float simg[400];
    __shared__ float sw[9800];
    int b = blockIdx.x;
    int t = threadIdx.x;  // 256
    for (int i = t; i < 400; i += 256) simg[i] = img[b * 400 + i];
    for (int i = t; i < 9800; i += 256) sw[i] = conv_w[i];
    __syncthreads();
    for (int o = t; o < FLATK; o += 256) {
        int f = o / 196;
        int ij = o % 196;
        int i = ij / 14, j = ij % 14;
        const float* wp = &sw[f * 49];
        const float* ip = &simg[i * 20 + j];
        float acc = 0.f;
#pragma unroll
        for (int p = 0; p < 7; p++)
#pragma unroll
            for (int q = 0; q < 7; q++)
                acc += ip[p * 20 + q] * wp[p * 7 + q];
        conv_raw[(size_t)b * FLATK + o] = acc;
    }
}

// ---------------- bn1 stats: per-filter sum/sq over (b, i, j) ----------------
__global__ void bn1_stats_kernel(const float* __restrict__ conv_raw,
                                 float* __restrict__ sum, float* __restrict__ sq) {
    int blk = blockIdx.x;          // b*200 + f, 102400 blocks
    int f = blk % 200;
    size_t base = (size_t)blk * 196;
    int lane = threadIdx.x;        // 64
    float s = 0.f, q = 0.f;
    for (int i = lane; i < 196; i += 64) {
        float v = conv_raw[base + i];
        s += v; q += v * v;
    }
    for (int o = 32; o > 0; o >>= 1) {
        s += __shfl_down(s, o, 64);
        q += __shfl_down(q, o, 64);
    }
    if (lane == 0) { atomicAdd(&sum[f], s); atomicAdd(&sq[f], q); }
}

__global__ void bn1_coef_kernel(const float* __restrict__ sum, const float* __restrict__ sq,
                                const float* __restrict__ g1, const float* __restrict__ b1,
                                float* __restrict__ s1, float* __restrict__ t1) {
    int f = threadIdx.x;
    if (f >= 200) return;
    const float inv_n = 1.0f / (BATCH * 196);
    float m = sum[f] * inv_n;
    float var = sq[f] * inv_n - m * m;
    float s = g1[f] * rsqrtf(var + EPSV);
    s1[f] = s;
    t1[f] = b1[f] - m * s;
}

// ---------------- FC GEMM v2: M=64 x N=200(full) x BK=32, split-K Z=49 ----------------
__global__ void gemm_fc(const float* __restrict__ conv_raw, const float* __restrict__ fc_w,
                        const float* __restrict__ s1g, const float* __restrict__ t1g,
                        float* __restrict__ fc_acc) {
    __shared__ float As[32][68];
    __shared__ float Bs[32][256];
    __shared__ float Ss1[200], St1[200];
    const int m0   = blockIdx.x * 64;
    const int kbeg = blockIdx.y * 800;
    const int tid  = threadIdx.x;
    const int tx = tid & 63, ty = tid >> 6;
    const int ar  = tid >> 2;
    const int akc = (tid & 3) * 8;

    for (int i = tid; i < 200; i += 256) { Ss1[i] = s1g[i]; St1[i] = t1g[i]; }
    __syncthreads();

    float acc[16][4] = {};
    for (int k0 = 0; k0 < 800; k0 += 32) {
        {
            const float4* gp = (const float4*)&conv_raw[(size_t)(m0 + ar) * FLATK + kbeg + k0 + akc];
            float4 v0 = gp[0], v1 = gp[1];
            float tmp[8] = {v0.x, v0.y, v0.z, v0.w, v1.x, v1.y, v1.z, v1.w};
#pragma unroll
            for (int j = 0; j < 8; j++) {
                int kg = kbeg + k0 + akc + j;
                int f = kg / 196;
                As[akc + j][ar] = fmaxf(tmp[j] * Ss1[f] + St1[f], 0.f);
            }
        }
        {
            const float4* gp = (const float4*)&fc_w[(size_t)(kbeg + k0) * 200];
            for (int idx = tid; idx < 1600; idx += 256) {
                float4 v = gp[idx];
                int k = idx / 50, n4 = (idx % 50) * 4;
                *(float4*)&Bs[k][n4] = v;
            }
        }
        __syncthreads();
#pragma unroll 4
        for (int k = 0; k < 32; k++) {
            float4 a0 = *(const float4*)&As[k][ty * 16];
            float4 a1 = *(const float4*)&As[k][ty * 16 + 4];
            float4 a2 = *(const float4*)&As[k][ty * 16 + 8];
            float4 a3 = *(const float4*)&As[k][ty * 16 + 12];
            float av[16] = {a0.x, a0.y, a0.z, a0.w, a1.x, a1.y, a1.z, a1.w,
                            a2.x, a2.y, a2.z, a2.w, a3.x, a3.y, a3.z, a3.w};
            float bv[4] = {Bs[k][tx], Bs[k][tx + 64], Bs[k][tx + 128], Bs[k][tx + 192]};
#pragma unroll
            for (int i = 0; i < 16; i++)
#pragma unroll
                for (int j = 0; j < 4; j++) acc[i][j] += av[i] * bv[j];
        }
        __syncthreads();
    }
#pragma unroll
    for (int i = 0; i < 16; i++) {
        int m = m0 + ty * 16 + i;
#pragma unroll
        for (int j = 0; j < 4; j++) {
            int n = tx + 64 * j;
            if (n < DD) atomicAdd(&fc_acc[(size_t)m * DD + n], acc[i][j]);
        }
    }
}

// ---------------- bn2 stats over batch per feature ----------------
__global__ void bn2_stats_kernel(const float* __restrict__ fc_acc, const float* __restrict__ fc_b,
                                 float* __restrict__ sum, float* __restrict__ sq) {
    int f = blockIdx.x;      // 200
    int lane = threadIdx.x;  // 64
    float s = 0.f, q = 0.f;
    float bb = fc_b[f];
    for (int b = lane; b < BATCH; b += 64) {
        float v = fc_acc[(size_t)b * DD + f] + bb;
        s += v; q += v * v;
    }
    for (int o = 32; o > 0; o >>= 1) {
        s += __shfl_down(s, o, 64);
        q += __shfl_down(q, o, 64);
    }
    if (lane == 0) { sum[f] = s; sq[f] = q; }
}

__global__ void hfin_kernel(const float* __restrict__ fc_acc, const float* __restrict__ fc_b,
                            const float* __restrict__ sum, const float* __restrict__ sq,
                            const float* __restrict__ g2, const float* __restrict__ b2,
                            float* __restrict__ hfin) {
    int e = blockIdx.x * blockDim.x + threadIdx.x;
    if (e >= BATCH * DD) return;
    int f = e % DD;
    float m = sum[f] * (1.0f / BATCH);
    float var = sq[f] * (1.0f / BATCH) - m * m;
    float v = (fc_acc[e] + fc_b[f] - m) * rsqrtf(var + EPSV) * g2[f] + b2[f];
    hfin[e] = fmaxf(v, 0.f);
}

// ---------------- logits GEMM v3: 128x128 tile, double-buffered, split-B banks ----------------
__launch_bounds__(256, 2)
__global__ void gemm_logits(const float* __restrict__ hfin, const float* __restrict__ x2,
                            const float* __restrict__ ent_bias, float* __restrict__ out) {
    __shared__ float As[2][8][132];
    __shared__ float Bs[2][8][132];
    const int m0 = blockIdx.x * 128;
    const int n0 = blockIdx.y * 128;
    const int tid = threadIdx.x;
    const int tx = tid & 15, ty = tid >> 4;
    const int lr  = tid >> 1;          // 0..127
    const int lkc = (tid & 1) * 4;     // 0,4
    const int gn = n0 + lr;
    const bool nval = gn < N_ENTS;

    auto loadA = [&](int k0) -> float4 {
        return *(const float4*)&hfin[(size_t)(m0 + lr) * DD + k0 + lkc];
    };
    auto loadB = [&](int k0) -> float4 {
        float4 v = make_float4(0.f, 0.f, 0.f, 0.f);
        if (nval) v = *(const float4*)&x2[(size_t)gn * DD + k0 + lkc];
        return v;
    };
    auto stage = [&](float4 va, float4 vb, int buf) {
        As[buf][lkc + 0][lr] = va.x; As[buf][lkc + 1][lr] = va.y;
        As[buf][lkc + 2][lr] = va.z; As[buf][lkc + 3][lr] = va.w;
        Bs[buf][lkc + 0][lr] = vb.x; Bs[buf][lkc + 1][lr] = vb.y;
        Bs[buf][lkc + 2][lr] = vb.z; Bs[buf][lkc + 3][lr] = vb.w;
    };

    float acc[8][8] = {};
    stage(loadA(0), loadB(0), 0);
    __syncthreads();
    int cur = 0;

    for (int k0 = 0; k0 < DD; k0 += 8) {
        const int nxt = k0 + 8;
        const bool have = nxt < DD;
        float4 na = make_float4(0.f, 0.f, 0.f, 0.f), nb = na;
        if (have) { na = loadA(nxt); nb = loadB(nxt); }
#pragma unroll
        for (int k = 0; k < 8; k++) {
            float4 a0 = *(const float4*)&As[cur][k][ty * 8];
            float4 a1 = *(const float4*)&As[cur][k][ty * 8 + 4];
            float4 b0 = *(const float4*)&Bs[cur][k][tx * 4];
            float4 b1 = *(const float4*)&Bs[cur][k][64 + tx * 4];
            float av[8] = {a0.x, a0.y, a0.z, a0.w, a1.x, a1.y, a1.z, a1.w};
            float bv[8] = {b0.x, b0.y, b0.z, b0.w, b1.x, b1.y, b1.z, b1.w};
#pragma unroll
            for (int i = 0; i < 8; i++)
#pragma unroll
                for (int j = 0; j < 8; j++) acc[i][j] += av[i] * bv[j];
        }
        if (have) {
            stage(na, nb, cur ^ 1);
            __syncthreads();
            cur ^= 1;
        }
    }

    // epilogue: + ent_bias, sigmoid; cols {nb0..nb0+3} and {nb1..nb1+3} (4-aligned, N_ENTS%4==0)
    const int nb0 = n0 + tx * 4;
    const int nb1 = n0 + 64 + tx * 4;
    const bool v0 = (nb0 + 3) < N_ENTS;
    const bool v1 = (nb1 + 3) < N_ENTS;
    float4 e0 = make_float4(0.f, 0.f, 0.f, 0.f), e1 = e0;
    if (v0) e0 = *(const float4*)&ent_bias[nb0];
    if (v1) e1 = *(const float4*)&ent_bias[nb1];
    float eb[8] = {e0.x, e0.y, e0.z, e0.w, e1.x, e1.y, e1.z, e1.w};
#pragma unroll
    for (int i = 0; i < 8; i++) {
        int m = m0 + ty * 8 + i;   // always < BATCH
        float o[8];
#pragma unroll
        for (int j = 0; j < 8; j++) {
            float v = acc[i][j] + eb[j];
            o[j] = 1.0f / (1.0f + __expf(-v));
        }
        if (v0) *(float4*)&out[(size_t)m * N_ENTS + nb0] = make_float4(o[0], o[1], o[2], o[3]);
        if (v1) *(float4*)&out[(size_t)m * N_ENTS + nb1] = make_float4(o[4], o[5], o[6], o[7]);
    }
}

// ================= host launch =================
extern "C" void kernel_launch(void* const* d_in, const int* in_sizes, int n_in,
                              void* d_out, int out_size, void* d_ws, size_t ws_size,
                              hipStream_t stream) {
    const int*   sub        = (const int*)d_in[0];
    const int*   rel        = (const int*)d_in[1];
    const int*   edge_index = (const int*)d_in[2];
    const int*   edge_type  = (const int*)d_in[3];
    const float* init_embed = (const float*)d_in[4];
    const float* init_rel   = (const float*)d_in[5];
    const float* w_in1      = (const float*)d_in[6];
    const float* w_out1     = (const float*)d_in[7];
    const float* w_loop1    = (const float*)d_in[8];
    const float* w_rel1     = (const float*)d_in[9];
    const float* loop_rel1  = (const float*)d_in[10];
    const float* bn_g1      = (const float*)d_in[11];
    const float* bn_b1      = (const float*)d_in[12];
    const float* w_in2      = (const float*)d_in[13];
    const float* w_out2     = (const float*)d_in[14];
    const float* w_loop2    = (const float*)d_in[15];
    const float* w_rel2     = (const float*)d_in[16];
    const float* loop_rel2  = (const float*)d_in[17];
    const float* bn_g2      = (const float*)d_in[18];
    const float* bn_b2      = (const float*)d_in[19];
    const float* conv_w     = (const float*)d_in[20];
    const float* bn0_g      = (const float*)d_in[21];
    const float* bn0_b      = (const float*)d_in[22];
    const float* bn1_g      = (const float*)d_in[23];
    const float* bn1_b      = (const float*)d_in[24];
    const float* bn2_g      = (const float*)d_in[25];
    const float* bn2_b      = (const float*)d_in[26];
    const float* fc_w       = (const float*)d_in[27];
    const float* fc_b       = (const float*)d_in[28];
    const float* ent_bias   = (const float*)d_in[29];

    float* ws = (float*)d_ws;
    float* x1       = ws + WS_X1;
    float* x2       = ws + WS_X2;
    float* r1       = ws + WS_R1;
    float* r2       = ws + WS_R2;
    float* dinv_in  = ws + WS_DINV_IN;
    float* dinv_out = ws + WS_DINV_OUT;
    float* stats    = ws + WS_STATS;
    float* imgraw   = ws + WS_IMGRAW;
    float* img      = ws + WS_IMG;
    float* fc_acc   = ws + WS_FCACC;
    float* hfin     = ws + WS_HFIN;
    float* big      = ws + WS_BIG;   // agg1 (10M) / agg2 (20M) / conv_raw (20.07M)
    float* out      = (float*)d_out;

    // CSR sort scratch lives in the x2 region (free until gemm_layer<200> writes x2)
    int* cnt    = (int*)x2;                 // NKEY
    int* startp = cnt + NKEY;               // NKEY+1
    int* col_s  = startp + NKEY + 1;        // E_TOT
    int* t_s    = col_s + E_TOT;            // E_TOT

    // zero accumulators (ws is poisoned 0xAA before every call)
    hipMemsetAsync(dinv_in, 0, 2 * N_ENTS * sizeof(float), stream);
    hipMemsetAsync(stats, 0, 4096 * sizeof(float), stream);
    hipMemsetAsync(fc_acc, 0, BATCH * DD * sizeof(float), stream);
    hipMemsetAsync(cnt, 0, NKEY * sizeof(int), stream);

    // degrees -> dinv
    deg_kernel<<<(E_TOT + 255) / 256, 256, 0, stream>>>(edge_index, dinv_in, dinv_out);
    dinv_kernel<<<(N_ENTS + 255) / 256, 256, 0, stream>>>(dinv_in, dinv_out);

    // CSR build (once; reused by both layers)
    hist_kernel<<<(E_TOT + 255) / 256, 256, 0, stream>>>(edge_index, cnt);
    scan_kernel<<<1, 1024, 0, stream>>>(cnt, startp);
    fill_kernel<<<(E_TOT + 255) / 256, 256, 0, stream>>>(edge_index, edge_type, startp, col_s, t_s);

    // ---- layer 1 ----  (agg stride 200 = in|out halves; loop fused into gemm)
    seg_kernel<100, 200><<<NKEY, 128, 0, stream>>>(startp, cnt, col_s, t_s, init_embed,
                                                   init_rel, dinv_in, dinv_out, big);
    {
        dim3 g((N_ENTS + 127) / 128, (DD + 127) / 128);
        gemm_layer<100><<<g, 256, 0, stream>>>(big, init_embed, loop_rel1,
                                               w_in1, w_out1, w_loop1, dinv_in, dinv_out, x1);
    }
    feat_stats_kernel<<<256, 256, 0, stream>>>(x1, N_ENTS, stats + ST_L1_SUM, stats + ST_L1_SQ);
    layer_apply_kernel<<<(N_ENTS * DD + 255) / 256, 256, 0, stream>>>(x1, stats + ST_L1_SUM,
                                                                      stats + ST_L1_SQ, bn_g1, bn_b1);
    rel_kernel<100><<<N_RELS, 256, 0, stream>>>(init_rel, w_rel1, r1);

    // ---- layer 2 ----  (agg stride 400)
    seg_kernel<200, 400><<<NKEY, 256, 0, stream>>>(startp, cnt, col_s, t_s, x1, r1,
                                                   dinv_in, dinv_out, big);
    {
        dim3 g((N_ENTS + 127) / 128, (DD + 127) / 128);
        gemm_layer<200><<<g, 256, 0, stream>>>(big, x1, loop_rel2,
                                               w_in2, w_out2, w_loop2, dinv_in, dinv_out, x2);
    }
    feat_stats_kernel<<<256, 256, 0, stream>>>(x2, N_ENTS, stats + ST_L2_SUM, stats + ST_L2_SQ);
    layer_apply_kernel<<<(N_ENTS * DD + 255) / 256, 256, 0, stream>>>(x2, stats + ST_L2_SUM,
                                                                      stats + ST_L2_SQ, bn_g2, bn_b2);
    rel_kernel<200><<<N_RELS, 256, 0, stream>>>(r1, w_rel2, r2);

    // ---- ConvE scorer ----
    gather_kernel<<<BATCH, 512, 0, stream>>>(sub, rel, x2, r2, imgraw, stats + ST_BN0);
    bn0_apply_kernel<<<(BATCH * 400 + 255) / 256, 256, 0, stream>>>(imgraw, stats + ST_BN0,
                                                                    bn0_g, bn0_b, img);
    conv_kernel<<<BATCH, 256, 0, stream>>>(img, conv_w, big);   // big = conv_raw now
    bn1_stats_kernel<<<BATCH * NFILT, 64, 0, stream>>>(big, stats + ST_BN1_SUM, stats + ST_BN1_SQ);
    bn1_coef_kernel<<<1, 256, 0, stream>>>(stats + ST_BN1_SUM, stats + ST_BN1_SQ, bn1_g, bn1_b,
                                           stats + ST_S1, stats + ST_T1);
    {
        dim3 g(BATCH / 64, 49);   // split-K: 49 chunks of 800
        gemm_fc<<<g, 256, 0, stream>>>(big, fc_w, stats + ST_S1, stats + ST_T1, fc_acc);
    }
    bn2_stats_kernel<<<NFILT, 64, 0, stream>>>(fc_acc, fc_b, stats + ST_BN2_SUM, stats + ST_BN2_SQ);
    hfin_kernel<<<(BATCH * DD + 255) / 256, 256, 0, stream>>>(fc_acc, fc_b, stats + ST_BN2_SUM,
                                                              stats + ST_BN2_SQ, bn2_g, bn2_b, hfin);
    {
        dim3 g(BATCH / 128, (N_ENTS + 127) / 128);
        gemm_logits<<<g, 256, 0, stream>>>(hfin, x2, ent_bias, out);
    }
}